// Round 1
// baseline (6029.572 us; speedup 1.0000x reference)
//
#include <hip/hip_runtime.h>
#include <math.h>

#define NB 32
#define NT 512
#define ND 256
#define NH 4
#define NLAYER 6
#define TOUT 2048

// ---------------- workspace layout (float offsets) ----------------
#define OFF_X    0ull          // 4,194,304   x / fused  [B,T,256]
#define OFF_FFH  4194304ull    // 16,777,216  ffn hidden [16384,1024]; later dec d1 [B,2048,256]
#define OFF_QKV  20971520ull   // 12,582,912  qkv [16384,768]; later dec d2 [B,2048,128]
#define OFF_ATTN 33554432ull   // 4,194,304   attn out; later dp h1
#define OFF_PROJ 37748736ull   // 4,194,304   proj / ff2 out; later dp h2
#define OFF_E    41943040ull   // 8192        emotion e [B,256]
#define OFF_INT  41951232ull   // 131072 ints: dur, starts, totals, tok
// total = 42,082,304 floats = 168.3 MB

// ---------------- embedding + positional encoding ----------------
__global__ __launch_bounds__(256) void embed_kernel(const int* __restrict__ text,
                                                    const float* __restrict__ emb,
                                                    float* __restrict__ x)
{
    const int row = blockIdx.x;            // b*512 + t
    const int d = threadIdx.x;
    const int t = row & (NT - 1);
    const int id = text[row];
    const int j2 = (d >> 1) * 2;
    const float c = -9.210340371976184f / 256.0f;   // -ln(10000)/D
    float freq = expf((float)j2 * c);
    float ang = (float)t * freq;
    float pe = (d & 1) ? cosf(ang) : sinf(ang);
    x[(size_t)row * ND + d] = emb[(size_t)id * ND + d] + pe;
}

// ---------------- fp32 tiled GEMM: C[M,N] = A[M,K] @ B[K,N] + bias ----------------
template<bool RELU>
__global__ __launch_bounds__(256) void gemm_kernel(const float* __restrict__ A,
                                                   const float* __restrict__ B,
                                                   const float* __restrict__ bias,
                                                   float* __restrict__ C,
                                                   int M, int N, int K)
{
    __shared__ float As[16][68];   // [k][m], pitch 68 keeps 16B align + low write conflicts
    __shared__ float Bs[16][64];   // [k][n]
    const int tid = threadIdx.x;
    const int tx = tid & 15, ty = tid >> 4;
    const int row0 = blockIdx.y * 64, col0 = blockIdx.x * 64;
    const int ar = tid >> 2, ak4 = (tid & 3) << 2;
    const int bk = tid >> 4, bn4 = (tid & 15) << 2;
    float acc[4][4] = {};
    for (int k0 = 0; k0 < K; k0 += 16) {
        float4 av = *(const float4*)(A + (size_t)(row0 + ar) * K + k0 + ak4);
        float4 bv = *(const float4*)(B + (size_t)(k0 + bk) * N + col0 + bn4);
        As[ak4 + 0][ar] = av.x;
        As[ak4 + 1][ar] = av.y;
        As[ak4 + 2][ar] = av.z;
        As[ak4 + 3][ar] = av.w;
        *(float4*)&Bs[bk][bn4] = bv;
        __syncthreads();
#pragma unroll
        for (int k = 0; k < 16; ++k) {
            float4 a = *(const float4*)&As[k][ty << 2];
            float4 b = *(const float4*)&Bs[k][tx << 2];
            float aa[4] = {a.x, a.y, a.z, a.w};
            float bb[4] = {b.x, b.y, b.z, b.w};
#pragma unroll
            for (int i = 0; i < 4; ++i)
#pragma unroll
                for (int j = 0; j < 4; ++j)
                    acc[i][j] = fmaf(aa[i], bb[j], acc[i][j]);
        }
        __syncthreads();
    }
    const int col = col0 + (tx << 2);
    float4 bv = *(const float4*)(bias + col);
#pragma unroll
    for (int i = 0; i < 4; ++i) {
        int row = row0 + (ty << 2) + i;
        float4 r;
        r.x = acc[i][0] + bv.x;
        r.y = acc[i][1] + bv.y;
        r.z = acc[i][2] + bv.z;
        r.w = acc[i][3] + bv.w;
        if (RELU) {
            r.x = fmaxf(r.x, 0.f); r.y = fmaxf(r.y, 0.f);
            r.z = fmaxf(r.z, 0.f); r.w = fmaxf(r.w, 0.f);
        }
        *(float4*)(C + (size_t)row * N + col) = r;
    }
}

// ---------------- attention: one WG per (b, h, 32-row q block) ----------------
__global__ __launch_bounds__(256) void attn_kernel(const float* __restrict__ qkv,
                                                   float* __restrict__ out)
{
    __shared__ float sQ[64][36];    // [d][r]  transposed
    __shared__ float sKV[64][132];  // [d][s]  transposed, 128-s chunk
    __shared__ float sS[32][516];   // scores
    const int tid = threadIdx.x;
    const int tb = blockIdx.x, h = blockIdx.y, b = blockIdx.z;
    const int t0 = tb * 32;
    const size_t base = (size_t)b * NT * 768;
    const int qoff = h * 64;

    // stage Q transposed [d][r]
    for (int i = tid; i < 32 * 16; i += 256) {
        int r = i >> 4, d4 = (i & 15) << 2;
        float4 v = *(const float4*)&qkv[base + (size_t)(t0 + r) * 768 + qoff + d4];
        sQ[d4 + 0][r] = v.x; sQ[d4 + 1][r] = v.y;
        sQ[d4 + 2][r] = v.z; sQ[d4 + 3][r] = v.w;
    }
    const int rg = tid >> 5;     // row group 0..7 (rows rg*4..rg*4+3)
    const int cg = tid & 31;     // col group within chunk (cols cg*4..)

    // ---- scores: S = Q K^T * 0.125 ----
    for (int ch = 0; ch < 4; ++ch) {
        const int s0 = ch * 128;
        for (int i = tid; i < 128 * 16; i += 256) {
            int s = i >> 4, d4 = (i & 15) << 2;
            float4 v = *(const float4*)&qkv[base + (size_t)(s0 + s) * 768 + 256 + qoff + d4];
            sKV[d4 + 0][s] = v.x; sKV[d4 + 1][s] = v.y;
            sKV[d4 + 2][s] = v.z; sKV[d4 + 3][s] = v.w;
        }
        __syncthreads();
        float acc[4][4] = {};
#pragma unroll
        for (int d = 0; d < 64; ++d) {
            float4 q4 = *(const float4*)&sQ[d][rg << 2];
            float4 k4 = *(const float4*)&sKV[d][cg << 2];
            float qa[4] = {q4.x, q4.y, q4.z, q4.w};
            float ka[4] = {k4.x, k4.y, k4.z, k4.w};
#pragma unroll
            for (int i = 0; i < 4; ++i)
#pragma unroll
                for (int j = 0; j < 4; ++j)
                    acc[i][j] = fmaf(qa[i], ka[j], acc[i][j]);
        }
#pragma unroll
        for (int i = 0; i < 4; ++i) {
            float4 r = make_float4(acc[i][0] * 0.125f, acc[i][1] * 0.125f,
                                   acc[i][2] * 0.125f, acc[i][3] * 0.125f);
            *(float4*)&sS[(rg << 2) + i][s0 + (cg << 2)] = r;
        }
        __syncthreads();
    }

    // ---- softmax: 8 lanes per row, stride-8 columns (bank-clean) ----
    {
        const int r = tid >> 3, p = tid & 7;
        float mx = -1e30f;
        for (int j = 0; j < 64; ++j) mx = fmaxf(mx, sS[r][(j << 3) + p]);
        for (int o = 1; o < 8; o <<= 1) mx = fmaxf(mx, __shfl_xor(mx, o));
        float sum = 0.f;
        for (int j = 0; j < 64; ++j) {
            float e = expf(sS[r][(j << 3) + p] - mx);
            sS[r][(j << 3) + p] = e;
            sum += e;
        }
        for (int o = 1; o < 8; o <<= 1) sum += __shfl_xor(sum, o);
        float inv = 1.0f / sum;
        for (int j = 0; j < 64; ++j) sS[r][(j << 3) + p] *= inv;
    }
    __syncthreads();

    // ---- O = P V ----
    const int dg = tid & 31;   // output d pair: dg*2, dg*2+1
    float accO[4][2] = {};
    for (int ch = 0; ch < 4; ++ch) {
        const int s0 = ch * 128;
        for (int i = tid; i < 128 * 16; i += 256) {
            int s = i >> 4, d4 = (i & 15) << 2;
            float4 v = *(const float4*)&qkv[base + (size_t)(s0 + s) * 768 + 512 + qoff + d4];
            sKV[d4 + 0][s] = v.x; sKV[d4 + 1][s] = v.y;
            sKV[d4 + 2][s] = v.z; sKV[d4 + 3][s] = v.w;
        }
        __syncthreads();
#pragma unroll
        for (int sq = 0; sq < 32; ++sq) {
            float4 a[4];
#pragma unroll
            for (int i = 0; i < 4; ++i)
                a[i] = *(const float4*)&sS[(rg << 2) + i][s0 + (sq << 2)];
            float4 v0 = *(const float4*)&sKV[(dg << 1) + 0][sq << 2];
            float4 v1 = *(const float4*)&sKV[(dg << 1) + 1][sq << 2];
#pragma unroll
            for (int i = 0; i < 4; ++i) {
                accO[i][0] += a[i].x * v0.x + a[i].y * v0.y + a[i].z * v0.z + a[i].w * v0.w;
                accO[i][1] += a[i].x * v1.x + a[i].y * v1.y + a[i].z * v1.z + a[i].w * v1.w;
            }
        }
        __syncthreads();
    }
#pragma unroll
    for (int i = 0; i < 4; ++i) {
        size_t o = ((size_t)b * NT + t0 + (rg << 2) + i) * ND + qoff + (dg << 1);
        out[o]     = accO[i][0];
        out[o + 1] = accO[i][1];
    }
}

// ---------------- x = LayerNorm(x + y) ----------------
__global__ __launch_bounds__(256) void add_ln_kernel(float* __restrict__ x,
                                                     const float* __restrict__ y,
                                                     const float* __restrict__ g,
                                                     const float* __restrict__ bta)
{
    __shared__ float red[8];
    const size_t row = blockIdx.x;
    const int d = threadIdx.x;
    float v = x[row * ND + d] + y[row * ND + d];
    float s = v;
#pragma unroll
    for (int o = 32; o; o >>= 1) s += __shfl_down(s, o);
    if ((d & 63) == 0) red[d >> 6] = s;
    __syncthreads();
    float m = (red[0] + red[1] + red[2] + red[3]) * (1.0f / 256.0f);
    float dv = v - m;
    float s2 = dv * dv;
#pragma unroll
    for (int o = 32; o; o >>= 1) s2 += __shfl_down(s2, o);
    if ((d & 63) == 0) red[4 + (d >> 6)] = s2;
    __syncthreads();
    float var = (red[4] + red[5] + red[6] + red[7]) * (1.0f / 256.0f);
    float r = 1.0f / sqrtf(var + 1e-5f);
    x[row * ND + d] = dv * r * g[d] + bta[d];
}

// ---------------- emotion MLP: e[b,d] ----------------
__global__ __launch_bounds__(256) void emotion_kernel(const float* __restrict__ emo,
                                                      const float* __restrict__ We1,
                                                      const float* __restrict__ be1,
                                                      const float* __restrict__ We2,
                                                      const float* __restrict__ be2,
                                                      float* __restrict__ e)
{
    const int b = blockIdx.x, d = threadIdx.x;
    const float em = emo[b];
    float acc = be2[d];
    for (int j = 0; j < 64; ++j) {
        float h = fmaxf(em * We1[j] + be1[j], 0.0f);
        acc = fmaf(h, We2[j * ND + d], acc);
    }
    e[b * ND + d] = acc;
}

__global__ __launch_bounds__(256) void addfuse_kernel(float* __restrict__ x,
                                                      const float* __restrict__ e)
{
    const int row = blockIdx.x;
    const int d = threadIdx.x;
    x[(size_t)row * ND + d] += e[(row >> 9) * ND + d];
}

// ---------------- generic conv over t-major [B,T,CIN] -> [B,T,COUT] ----------------
template<int CIN, int COUT, int KS, int TT, bool RELU, bool BN, bool GATHER>
__global__ __launch_bounds__(COUT) void conv_kernel(const float* __restrict__ in,
                                                    const float* __restrict__ w,
                                                    const float* __restrict__ bias,
                                                    const float* __restrict__ bng,
                                                    const float* __restrict__ bnb,
                                                    const float* __restrict__ bnm,
                                                    const float* __restrict__ bnv,
                                                    const int* __restrict__ tok,
                                                    float* __restrict__ out,
                                                    int T, int in_T)
{
    constexpr int PADK = (KS - 1) / 2;
    constexpr int ROWS = TT + KS - 1;
    __shared__ float s_in[ROWS][CIN];
    const int b = blockIdx.y;
    const int t0 = blockIdx.x * TT;
    const int o = threadIdx.x;
    for (int idx = threadIdx.x; idx < ROWS * (CIN / 4); idx += COUT) {
        int r = idx / (CIN / 4);
        int c4 = (idx - r * (CIN / 4)) << 2;
        int t = t0 + r - PADK;
        float4 v = make_float4(0.f, 0.f, 0.f, 0.f);
        if (t >= 0 && t < T) {
            long srow;
            if (GATHER) {
                int tk = tok[b * T + t];
                srow = (tk >= 0) ? ((long)b * in_T + tk) : -1;
            } else {
                srow = (long)b * T + t;
            }
            if (srow >= 0) v = *(const float4*)&in[srow * CIN + c4];
        }
        *(float4*)&s_in[r][c4] = v;
    }
    __syncthreads();
    float acc[TT];
    const float bs = bias[o];
#pragma unroll
    for (int t = 0; t < TT; ++t) acc[t] = bs;
    for (int c = 0; c < CIN; ++c) {
        float wv[KS];
#pragma unroll
        for (int k = 0; k < KS; ++k) wv[k] = w[(o * CIN + c) * KS + k];
        float col[ROWS];
#pragma unroll
        for (int r = 0; r < ROWS; ++r) col[r] = s_in[r][c];
#pragma unroll
        for (int t = 0; t < TT; ++t) {
            float a = acc[t];
#pragma unroll
            for (int k = 0; k < KS; ++k) a = fmaf(col[t + k], wv[k], a);
            acc[t] = a;
        }
    }
    float gg = 1.f, mb = 0.f, bt = 0.f, rs = 1.f;
    if (BN) {
        gg = bng[o]; bt = bnb[o]; mb = bnm[o];
        rs = 1.0f / sqrtf(bnv[o] + 1e-5f);
    }
#pragma unroll
    for (int t = 0; t < TT; ++t) {
        float yv = acc[t];
        if (RELU) yv = fmaxf(yv, 0.0f);
        if (BN) yv = gg * (yv - mb) * rs + bt;
        out[((size_t)b * T + t0 + t) * COUT + o] = yv;
    }
}

// ---------------- duration: log_dur -> dur ----------------
__global__ __launch_bounds__(256) void dur_kernel(const float* __restrict__ h2,
                                                  const float* __restrict__ wo,
                                                  const float* __restrict__ bo,
                                                  int* __restrict__ dur)
{
    __shared__ float red[4];
    const int row = blockIdx.x;
    const int c = threadIdx.x;
    float s = h2[(size_t)row * ND + c] * wo[c];
#pragma unroll
    for (int o = 32; o; o >>= 1) s += __shfl_down(s, o);
    if ((c & 63) == 0) red[c >> 6] = s;
    __syncthreads();
    if (c == 0) {
        float ld = red[0] + red[1] + red[2] + red[3] + bo[0];
        float d = rintf(expf(ld));          // round half-to-even, matches jnp.round
        d = fminf(fmaxf(d, 1.0f), 8.0f);
        dur[row] = (int)d;
    }
}

__global__ __launch_bounds__(64) void scan_kernel(const int* __restrict__ dur,
                                                  int* __restrict__ starts,
                                                  int* __restrict__ totals)
{
    const int b = threadIdx.x;
    if (b >= NB) return;
    int acc = 0;
    for (int t = 0; t < NT; ++t) {
        starts[b * NT + t] = acc;
        acc += dur[b * NT + t];
    }
    totals[b] = acc;
}

__global__ __launch_bounds__(256) void tok_kernel(const int* __restrict__ starts,
                                                  const int* __restrict__ totals,
                                                  int* __restrict__ tok)
{
    const int gid = blockIdx.x * 256 + threadIdx.x;   // 65536
    const int b = gid >> 11, p = gid & (TOUT - 1);
    const int total = totals[b];
    int res = -1;
    if (p < total) {
        const int* st = starts + b * NT;
        int lo = 0, hi = NT - 1;
        while (lo < hi) {
            int mid = (lo + hi + 1) >> 1;
            if (st[mid] <= p) lo = mid; else hi = mid - 1;
        }
        res = lo;
    }
    tok[gid] = res;
}

// ---------------- decoder conv3: [B,2048,128] -> wav [B,2048] ----------------
__global__ __launch_bounds__(256) void conv3_kernel(const float* __restrict__ in,
                                                    const float* __restrict__ w,
                                                    const float* __restrict__ bias,
                                                    float* __restrict__ out)
{
    const int gid = blockIdx.x * 256 + threadIdx.x;   // 65536
    const int b = gid >> 11, t = gid & (TOUT - 1);
    float acc = bias[0];
#pragma unroll
    for (int k = 0; k < 5; ++k) {
        int t2 = t + k - 2;
        if (t2 < 0 || t2 >= TOUT) continue;
        const float* row = in + ((size_t)b * TOUT + t2) * 128;
        for (int c = 0; c < 128; ++c) acc = fmaf(row[c], w[c * 5 + k], acc);
    }
    out[gid] = acc;
}

// ---------------- orchestration ----------------
extern "C" void kernel_launch(void* const* d_in, const int* in_sizes, int n_in,
                              void* d_out, int out_size, void* d_ws, size_t ws_size,
                              hipStream_t stream)
{
    const int*   text    = (const int*)d_in[0];
    const float* emotion = (const float*)d_in[1];
    const float* emb     = (const float*)d_in[2];
    const float* Wqkv    = (const float*)d_in[3];
    const float* bqkv    = (const float*)d_in[4];
    const float* Wo      = (const float*)d_in[5];
    const float* bo      = (const float*)d_in[6];
    const float* W1      = (const float*)d_in[7];
    const float* b1      = (const float*)d_in[8];
    const float* W2      = (const float*)d_in[9];
    const float* b2      = (const float*)d_in[10];
    const float* ln1g    = (const float*)d_in[11];
    const float* ln1b    = (const float*)d_in[12];
    const float* ln2g    = (const float*)d_in[13];
    const float* ln2b    = (const float*)d_in[14];
    const float* We1     = (const float*)d_in[15];
    const float* be1     = (const float*)d_in[16];
    const float* We2     = (const float*)d_in[17];
    const float* be2     = (const float*)d_in[18];
    const float* dp_w1   = (const float*)d_in[19];
    const float* dp_b1   = (const float*)d_in[20];
    const float* dp_g1   = (const float*)d_in[21];
    const float* dp_bt1  = (const float*)d_in[22];
    const float* dp_m1   = (const float*)d_in[23];
    const float* dp_v1   = (const float*)d_in[24];
    const float* dp_w2   = (const float*)d_in[25];
    const float* dp_b2   = (const float*)d_in[26];
    const float* dp_g2   = (const float*)d_in[27];
    const float* dp_bt2  = (const float*)d_in[28];
    const float* dp_m2   = (const float*)d_in[29];
    const float* dp_v2   = (const float*)d_in[30];
    const float* dp_wo   = (const float*)d_in[31];
    const float* dp_bo   = (const float*)d_in[32];
    const float* dec_w1  = (const float*)d_in[33];
    const float* dec_b1  = (const float*)d_in[34];
    const float* dec_w2  = (const float*)d_in[35];
    const float* dec_b2  = (const float*)d_in[36];
    const float* dec_w3  = (const float*)d_in[37];
    const float* dec_b3  = (const float*)d_in[38];

    float* ws   = (float*)d_ws;
    float* x    = ws + OFF_X;
    float* ffh  = ws + OFF_FFH;     // also dec d1
    float* qkvb = ws + OFF_QKV;     // also dec d2
    float* attb = ws + OFF_ATTN;    // also dp h1
    float* prjb = ws + OFF_PROJ;    // also dp h2
    float* ebuf = ws + OFF_E;
    int*   ip     = (int*)(ws + OFF_INT);
    int*   durb   = ip;              // 16384
    int*   startb = ip + 16384;      // 16384
    int*   totb   = ip + 32768;      // 32
    int*   tokb   = ip + 32832;      // 65536

    const int M = NB * NT;   // 16384

    embed_kernel<<<M, 256, 0, stream>>>(text, emb, x);

    for (int l = 0; l < NLAYER; ++l) {
        gemm_kernel<false><<<dim3(12, M / 64), 256, 0, stream>>>(
            x, Wqkv + (size_t)l * ND * 3 * ND, bqkv + l * 3 * ND, qkvb, M, 3 * ND, ND);
        attn_kernel<<<dim3(NT / 32, NH, NB), 256, 0, stream>>>(qkvb, attb);
        gemm_kernel<false><<<dim3(4, M / 64), 256, 0, stream>>>(
            attb, Wo + (size_t)l * ND * ND, bo + l * ND, prjb, M, ND, ND);
        add_ln_kernel<<<M, 256, 0, stream>>>(x, prjb, ln1g + l * ND, ln1b + l * ND);
        gemm_kernel<true><<<dim3(16, M / 64), 256, 0, stream>>>(
            x, W1 + (size_t)l * ND * 4 * ND, b1 + l * 4 * ND, ffh, M, 4 * ND, ND);
        gemm_kernel<false><<<dim3(4, M / 64), 256, 0, stream>>>(
            ffh, W2 + (size_t)l * 4 * ND * ND, b2 + l * ND, prjb, M, ND, 4 * ND);
        add_ln_kernel<<<M, 256, 0, stream>>>(x, prjb, ln2g + l * ND, ln2b + l * ND);
    }

    emotion_kernel<<<NB, 256, 0, stream>>>(emotion, We1, be1, We2, be2, ebuf);
    addfuse_kernel<<<M, 256, 0, stream>>>(x, ebuf);

    // duration predictor: conv(K=3) -> relu -> BN, twice; then pointwise -> dur
    conv_kernel<256, 256, 3, 32, true, true, false><<<dim3(NT / 32, NB), 256, 0, stream>>>(
        x, dp_w1, dp_b1, dp_g1, dp_bt1, dp_m1, dp_v1, nullptr, attb, NT, NT);
    conv_kernel<256, 256, 3, 32, true, true, false><<<dim3(NT / 32, NB), 256, 0, stream>>>(
        attb, dp_w2, dp_b2, dp_g2, dp_bt2, dp_m2, dp_v2, nullptr, prjb, NT, NT);
    dur_kernel<<<M, 256, 0, stream>>>(prjb, dp_wo, dp_bo, durb);
    scan_kernel<<<1, 64, 0, stream>>>(durb, startb, totb);
    tok_kernel<<<NB * TOUT / 256, 256, 0, stream>>>(startb, totb, tokb);

    // decoder: conv1 gathers regulated rows straight from fused x via tok[]
    conv_kernel<256, 256, 5, 32, true, false, true><<<dim3(TOUT / 32, NB), 256, 0, stream>>>(
        x, dec_w1, dec_b1, nullptr, nullptr, nullptr, nullptr, tokb, ffh, TOUT, NT);
    conv_kernel<256, 128, 5, 32, true, false, false><<<dim3(TOUT / 32, NB), 128, 0, stream>>>(
        ffh, dec_w2, dec_b2, nullptr, nullptr, nullptr, nullptr, nullptr, qkvb, TOUT, TOUT);
    conv3_kernel<<<NB * TOUT / 256, 256, 0, stream>>>(qkvb, dec_w3, dec_b3, (float*)d_out);
}

// Round 2
// 5483.738 us; speedup vs baseline: 1.0995x; 1.0995x over previous
//
#include <hip/hip_runtime.h>
#include <math.h>

#define NB 32
#define NT 512
#define ND 256
#define NH 4
#define NLAYER 6
#define TOUT 2048

// ---------------- workspace layout (float offsets) ----------------
#define OFF_X    0ull          // 4,194,304   x / fused  [B,T,256]
#define OFF_FFH  4194304ull    // 16,777,216  ffn hidden [16384,1024]; later dec d1 [B,2048,256]
#define OFF_QKV  20971520ull   // 12,582,912  qkv [16384,768]; later dec d2 [B,2048,128]
#define OFF_ATTN 33554432ull   // 4,194,304   attn out; later dp h1
#define OFF_PROJ 37748736ull   // 4,194,304   proj / ff2 out; later dp h2
#define OFF_E    41943040ull   // 8192        emotion e [B,256]
#define OFF_INT  41951232ull   // 131072 ints: dur, starts, totals, tok

// ---------------- embedding + positional encoding ----------------
__global__ __launch_bounds__(256) void embed_kernel(const int* __restrict__ text,
                                                    const float* __restrict__ emb,
                                                    float* __restrict__ x)
{
    const int row = blockIdx.x;            // b*512 + t
    const int d = threadIdx.x;
    const int t = row & (NT - 1);
    const int id = text[row];
    const int j2 = (d >> 1) * 2;
    const float c = -9.210340371976184f / 256.0f;   // -ln(10000)/D
    float freq = expf((float)j2 * c);
    float ang = (float)t * freq;
    float pe = (d & 1) ? cosf(ang) : sinf(ang);
    x[(size_t)row * ND + d] = emb[(size_t)id * ND + d] + pe;
}

// ---------------- fp32 single-wave GEMM: 64x64 tile, 8x8 split-frag micro ----------------
// C[M,N] = A[M,K] @ B[K,N] + bias, optional relu. WG = 64 threads = 1 wave.
template<bool RELU>
__global__ __launch_bounds__(64) void gemm64_kernel(const float* __restrict__ A,
                                                    const float* __restrict__ B,
                                                    const float* __restrict__ bias,
                                                    float* __restrict__ C,
                                                    int M, int N, int K)
{
    __shared__ float As[16 * 68];   // [k][m], pitch 68 (16B-aligned rows, 2-way max)
    __shared__ float Bs[16 * 68];   // [k][n]
    const int lane = threadIdx.x;
    const int row0 = blockIdx.y * 64, col0 = blockIdx.x * 64;
    const int r0 = (lane >> 3) << 2;   // {0,4,...,28}; rows r0..r0+3 and 32+r0..
    const int c0 = (lane & 7) << 2;    // {0,4,...,28}; cols c0..c0+3 and 32+c0..
    float acc[8][8] = {};              // [rhalf*4+i][chalf*4+j]

    for (int k0 = 0; k0 < K; k0 += 16) {
        // stage A transposed: As[k][m]
#pragma unroll
        for (int it = 0; it < 4; ++it) {
            int r = it * 16 + (lane >> 2);
            int kq = (lane & 3) << 2;
            float4 v = *(const float4*)&A[(size_t)(row0 + r) * K + k0 + kq];
            As[(kq + 0) * 68 + r] = v.x;
            As[(kq + 1) * 68 + r] = v.y;
            As[(kq + 2) * 68 + r] = v.z;
            As[(kq + 3) * 68 + r] = v.w;
        }
        // stage B natural: Bs[k][n]
#pragma unroll
        for (int it = 0; it < 4; ++it) {
            int kk = it * 4 + (lane >> 4);
            int n4 = (lane & 15) << 2;
            *(float4*)&Bs[kk * 68 + n4] =
                *(const float4*)&B[(size_t)(k0 + kk) * N + col0 + n4];
        }
        __syncthreads();
#pragma unroll
        for (int k = 0; k < 16; ++k) {
            float4 a0 = *(const float4*)&As[k * 68 + r0];
            float4 a1 = *(const float4*)&As[k * 68 + 32 + r0];
            float4 b0 = *(const float4*)&Bs[k * 68 + c0];
            float4 b1 = *(const float4*)&Bs[k * 68 + 32 + c0];
            float aa[8] = {a0.x, a0.y, a0.z, a0.w, a1.x, a1.y, a1.z, a1.w};
            float bb[8] = {b0.x, b0.y, b0.z, b0.w, b1.x, b1.y, b1.z, b1.w};
#pragma unroll
            for (int i = 0; i < 8; ++i)
#pragma unroll
                for (int j = 0; j < 8; ++j)
                    acc[i][j] = fmaf(aa[i], bb[j], acc[i][j]);
        }
        __syncthreads();
    }
    float4 bv0 = *(const float4*)(bias + col0 + c0);
    float4 bv1 = *(const float4*)(bias + col0 + 32 + c0);
    float bb[8] = {bv0.x, bv0.y, bv0.z, bv0.w, bv1.x, bv1.y, bv1.z, bv1.w};
#pragma unroll
    for (int ih = 0; ih < 2; ++ih)
#pragma unroll
        for (int i = 0; i < 4; ++i) {
            int row = row0 + ih * 32 + r0 + i;
#pragma unroll
            for (int jh = 0; jh < 2; ++jh) {
                float4 r;
                r.x = acc[ih * 4 + i][jh * 4 + 0] + bb[jh * 4 + 0];
                r.y = acc[ih * 4 + i][jh * 4 + 1] + bb[jh * 4 + 1];
                r.z = acc[ih * 4 + i][jh * 4 + 2] + bb[jh * 4 + 2];
                r.w = acc[ih * 4 + i][jh * 4 + 3] + bb[jh * 4 + 3];
                if (RELU) {
                    r.x = fmaxf(r.x, 0.f); r.y = fmaxf(r.y, 0.f);
                    r.z = fmaxf(r.z, 0.f); r.w = fmaxf(r.w, 0.f);
                }
                *(float4*)&C[(size_t)row * N + col0 + jh * 32 + c0] = r;
            }
        }
}

// ---------------- attention v2: online softmax, q-tile 64, chunk 64 ----------------
// LDS ~52KB -> 3 WG/CU. K stored [d][c] with XOR-swizzled f4 blocks; V natural [c][d];
// P stored c-major [c][r] so PV is an outer product over c.
#define SWZ(blk, d) ((((blk) ^ (d)) & 15) << 2)

__global__ __launch_bounds__(256) void attn2_kernel(const float* __restrict__ qkv,
                                                    float* __restrict__ out)
{
    __shared__ float sQT[64 * 64];   // Q^T [d][r], swizzled blocks, pitch 64
    __shared__ float sKV[64 * 68];   // K^T [d][c] swizzled pitch 64; then V [c][d] pitch 68
    __shared__ float sPT[64 * 68];   // P^T [c][r], pitch 68
    __shared__ float sM[64], sL[64], sA[64];
    const int tid = threadIdx.x;
    const int tb = blockIdx.x, h = blockIdx.y, b = blockIdx.z;
    const int t0 = tb * 64;
    const size_t base = (size_t)b * NT * 768;
    const int qoff = h * 64;
    const int g4 = tid >> 4;    // 0..15
    const int l4 = tid & 15;    // 0..15

    // stage Q transposed + swizzled
#pragma unroll
    for (int it = 0; it < 4; ++it) {
        int i = it * 256 + tid;
        int r = i >> 4, d4 = (i & 15) << 2;
        float4 v = *(const float4*)&qkv[base + (size_t)(t0 + r) * 768 + qoff + d4];
        float vv[4] = {v.x, v.y, v.z, v.w};
#pragma unroll
        for (int j = 0; j < 4; ++j)
            sQT[(d4 + j) * 64 + SWZ(r >> 2, d4 + j) + (r & 3)] = vv[j];
    }
    if (tid < 64) { sM[tid] = -3.0e38f; sL[tid] = 0.0f; }
    __syncthreads();

    float accO[4][4] = {};   // [d_i][r_j]

    for (int ch = 0; ch < 8; ++ch) {
        const int s0 = ch * 64;
        // global loads for K and V chunk (registers; V written to LDS later)
        float4 kreg[4], vreg[4];
#pragma unroll
        for (int it = 0; it < 4; ++it) {
            int i = it * 256 + tid;
            int c = i >> 4, d4 = (i & 15) << 2;
            kreg[it] = *(const float4*)&qkv[base + (size_t)(s0 + c) * 768 + 256 + qoff + d4];
            vreg[it] = *(const float4*)&qkv[base + (size_t)(s0 + c) * 768 + 512 + qoff + d4];
        }
        // write K^T swizzled
#pragma unroll
        for (int it = 0; it < 4; ++it) {
            int i = it * 256 + tid;
            int c = i >> 4, d4 = (i & 15) << 2;
            float kk[4] = {kreg[it].x, kreg[it].y, kreg[it].z, kreg[it].w};
#pragma unroll
            for (int j = 0; j < 4; ++j)
                sKV[(d4 + j) * 64 + SWZ(c >> 2, d4 + j) + (c & 3)] = kk[j];
        }
        __syncthreads();   // S1: K^T ready (also: prev chunk's PV done before overwrite)

        // scores: rows g4*4.., cols l4*4.. ; outer product over d
        float acc[4][4] = {};
#pragma unroll 8
        for (int d = 0; d < 64; ++d) {
            float4 qa = *(const float4*)&sQT[d * 64 + SWZ(g4, d)];
            float4 kb = *(const float4*)&sKV[d * 64 + SWZ(l4, d)];
            float qq[4] = {qa.x, qa.y, qa.z, qa.w};
            float kk[4] = {kb.x, kb.y, kb.z, kb.w};
#pragma unroll
            for (int i = 0; i < 4; ++i)
#pragma unroll
                for (int j = 0; j < 4; ++j)
                    acc[i][j] = fmaf(qq[i], kk[j], acc[i][j]);
        }
#pragma unroll
        for (int i = 0; i < 4; ++i)
#pragma unroll
            for (int j = 0; j < 4; ++j)
                acc[i][j] *= 0.125f;

        // online softmax per row (rows owned by the 16 lanes sharing g4)
#pragma unroll
        for (int i = 0; i < 4; ++i) {
            float m = fmaxf(fmaxf(acc[i][0], acc[i][1]), fmaxf(acc[i][2], acc[i][3]));
#pragma unroll
            for (int o = 1; o < 16; o <<= 1) m = fmaxf(m, __shfl_xor(m, o));
            float mo = sM[g4 * 4 + i];
            float nm = fmaxf(mo, m);
            float al = expf(mo - nm);
            float s = 0.f;
#pragma unroll
            for (int j = 0; j < 4; ++j) {
                float p = expf(acc[i][j] - nm);
                acc[i][j] = p;
                s += p;
            }
#pragma unroll
            for (int o = 1; o < 16; o <<= 1) s += __shfl_xor(s, o);
            if (l4 == 0) {
                sM[g4 * 4 + i] = nm;
                sL[g4 * 4 + i] = sL[g4 * 4 + i] * al + s;
                sA[g4 * 4 + i] = al;
            }
        }
        // write P^T [c][r]
#pragma unroll
        for (int j = 0; j < 4; ++j)
            *(float4*)&sPT[(l4 * 4 + j) * 68 + g4 * 4] =
                make_float4(acc[0][j], acc[1][j], acc[2][j], acc[3][j]);
        __syncthreads();   // S2: P^T + stats visible; all K reads done

        // write V natural [c][d]
#pragma unroll
        for (int it = 0; it < 4; ++it) {
            int i = it * 256 + tid;
            int c = i >> 4, d4 = (i & 15) << 2;
            *(float4*)&sKV[c * 68 + d4] = vreg[it];
        }
        __syncthreads();   // S3: V ready

        // PV: O^T[d][r] accumulate; a = V[c][d-frag] (d = g4*4..), b = P^T[c][r-frag] (r = l4*4..)
        float4 alj = *(const float4*)&sA[l4 * 4];
        float alv[4] = {alj.x, alj.y, alj.z, alj.w};
#pragma unroll
        for (int i = 0; i < 4; ++i)
#pragma unroll
            for (int j = 0; j < 4; ++j)
                accO[i][j] *= alv[j];
#pragma unroll 8
        for (int c = 0; c < 64; ++c) {
            float4 va = *(const float4*)&sKV[c * 68 + g4 * 4];
            float4 pb = *(const float4*)&sPT[c * 68 + l4 * 4];
            float vv[4] = {va.x, va.y, va.z, va.w};
            float pp[4] = {pb.x, pb.y, pb.z, pb.w};
#pragma unroll
            for (int i = 0; i < 4; ++i)
#pragma unroll
                for (int j = 0; j < 4; ++j)
                    accO[i][j] = fmaf(vv[i], pp[j], accO[i][j]);
        }
        __syncthreads();   // S4: protect sKV/sPT before next chunk overwrites
    }

    // epilogue: divide by l, write out[b, t0+r, qoff+d]
    float4 lf = *(const float4*)&sL[l4 * 4];
    float linv[4] = {1.f / lf.x, 1.f / lf.y, 1.f / lf.z, 1.f / lf.w};
#pragma unroll
    for (int j = 0; j < 4; ++j) {
        float4 r;
        r.x = accO[0][j] * linv[j];
        r.y = accO[1][j] * linv[j];
        r.z = accO[2][j] * linv[j];
        r.w = accO[3][j] * linv[j];
        *(float4*)&out[((size_t)b * NT + t0 + l4 * 4 + j) * ND + qoff + g4 * 4] = r;
    }
}

// ---------------- x = LayerNorm(x + y) ----------------
__global__ __launch_bounds__(256) void add_ln_kernel(float* __restrict__ x,
                                                     const float* __restrict__ y,
                                                     const float* __restrict__ g,
                                                     const float* __restrict__ bta)
{
    __shared__ float red[8];
    const size_t row = blockIdx.x;
    const int d = threadIdx.x;
    float v = x[row * ND + d] + y[row * ND + d];
    float s = v;
#pragma unroll
    for (int o = 32; o; o >>= 1) s += __shfl_down(s, o);
    if ((d & 63) == 0) red[d >> 6] = s;
    __syncthreads();
    float m = (red[0] + red[1] + red[2] + red[3]) * (1.0f / 256.0f);
    float dv = v - m;
    float s2 = dv * dv;
#pragma unroll
    for (int o = 32; o; o >>= 1) s2 += __shfl_down(s2, o);
    if ((d & 63) == 0) red[4 + (d >> 6)] = s2;
    __syncthreads();
    float var = (red[4] + red[5] + red[6] + red[7]) * (1.0f / 256.0f);
    float r = 1.0f / sqrtf(var + 1e-5f);
    x[row * ND + d] = dv * r * g[d] + bta[d];
}

// ---------------- emotion MLP: e[b,d] ----------------
__global__ __launch_bounds__(256) void emotion_kernel(const float* __restrict__ emo,
                                                      const float* __restrict__ We1,
                                                      const float* __restrict__ be1,
                                                      const float* __restrict__ We2,
                                                      const float* __restrict__ be2,
                                                      float* __restrict__ e)
{
    const int b = blockIdx.x, d = threadIdx.x;
    const float em = emo[b];
    float acc = be2[d];
    for (int j = 0; j < 64; ++j) {
        float h = fmaxf(em * We1[j] + be1[j], 0.0f);
        acc = fmaf(h, We2[j * ND + d], acc);
    }
    e[b * ND + d] = acc;
}

__global__ __launch_bounds__(256) void addfuse_kernel(float* __restrict__ x,
                                                      const float* __restrict__ e)
{
    const int row = blockIdx.x;
    const int d = threadIdx.x;
    x[(size_t)row * ND + d] += e[(row >> 9) * ND + d];
}

// ---------------- generic conv over t-major [B,T,CIN] -> [B,T,COUT] ----------------
template<int CIN, int COUT, int KS, int TT, bool RELU, bool BN, bool GATHER>
__global__ __launch_bounds__(COUT) void conv_kernel(const float* __restrict__ in,
                                                    const float* __restrict__ w,
                                                    const float* __restrict__ bias,
                                                    const float* __restrict__ bng,
                                                    const float* __restrict__ bnb,
                                                    const float* __restrict__ bnm,
                                                    const float* __restrict__ bnv,
                                                    const int* __restrict__ tok,
                                                    float* __restrict__ out,
                                                    int T, int in_T)
{
    constexpr int PADK = (KS - 1) / 2;
    constexpr int ROWS = TT + KS - 1;
    __shared__ float s_in[ROWS][CIN];
    const int b = blockIdx.y;
    const int t0 = blockIdx.x * TT;
    const int o = threadIdx.x;
    for (int idx = threadIdx.x; idx < ROWS * (CIN / 4); idx += COUT) {
        int r = idx / (CIN / 4);
        int c4 = (idx - r * (CIN / 4)) << 2;
        int t = t0 + r - PADK;
        float4 v = make_float4(0.f, 0.f, 0.f, 0.f);
        if (t >= 0 && t < T) {
            long srow;
            if (GATHER) {
                int tk = tok[b * T + t];
                srow = (tk >= 0) ? ((long)b * in_T + tk) : -1;
            } else {
                srow = (long)b * T + t;
            }
            if (srow >= 0) v = *(const float4*)&in[srow * CIN + c4];
        }
        *(float4*)&s_in[r][c4] = v;
    }
    __syncthreads();
    float acc[TT];
    const float bs = bias[o];
#pragma unroll
    for (int t = 0; t < TT; ++t) acc[t] = bs;
    for (int c = 0; c < CIN; ++c) {
        float wv[KS];
#pragma unroll
        for (int k = 0; k < KS; ++k) wv[k] = w[(o * CIN + c) * KS + k];
        float col[ROWS];
#pragma unroll
        for (int r = 0; r < ROWS; ++r) col[r] = s_in[r][c];
#pragma unroll
        for (int t = 0; t < TT; ++t) {
            float a = acc[t];
#pragma unroll
            for (int k = 0; k < KS; ++k) a = fmaf(col[t + k], wv[k], a);
            acc[t] = a;
        }
    }
    float gg = 1.f, mb = 0.f, bt = 0.f, rs = 1.f;
    if (BN) {
        gg = bng[o]; bt = bnb[o]; mb = bnm[o];
        rs = 1.0f / sqrtf(bnv[o] + 1e-5f);
    }
#pragma unroll
    for (int t = 0; t < TT; ++t) {
        float yv = acc[t];
        if (RELU) yv = fmaxf(yv, 0.0f);
        if (BN) yv = gg * (yv - mb) * rs + bt;
        out[((size_t)b * T + t0 + t) * COUT + o] = yv;
    }
}

// ---------------- duration: log_dur -> dur ----------------
__global__ __launch_bounds__(256) void dur_kernel(const float* __restrict__ h2,
                                                  const float* __restrict__ wo,
                                                  const float* __restrict__ bo,
                                                  int* __restrict__ dur)
{
    __shared__ float red[4];
    const int row = blockIdx.x;
    const int c = threadIdx.x;
    float s = h2[(size_t)row * ND + c] * wo[c];
#pragma unroll
    for (int o = 32; o; o >>= 1) s += __shfl_down(s, o);
    if ((c & 63) == 0) red[c >> 6] = s;
    __syncthreads();
    if (c == 0) {
        float ld = red[0] + red[1] + red[2] + red[3] + bo[0];
        float d = rintf(expf(ld));
        d = fminf(fmaxf(d, 1.0f), 8.0f);
        dur[row] = (int)d;
    }
}

__global__ __launch_bounds__(64) void scan_kernel(const int* __restrict__ dur,
                                                  int* __restrict__ starts,
                                                  int* __restrict__ totals)
{
    const int b = threadIdx.x;
    if (b >= NB) return;
    int acc = 0;
    for (int t = 0; t < NT; ++t) {
        starts[b * NT + t] = acc;
        acc += dur[b * NT + t];
    }
    totals[b] = acc;
}

__global__ __launch_bounds__(256) void tok_kernel(const int* __restrict__ starts,
                                                  const int* __restrict__ totals,
                                                  int* __restrict__ tok)
{
    const int gid = blockIdx.x * 256 + threadIdx.x;   // 65536
    const int b = gid >> 11, p = gid & (TOUT - 1);
    const int total = totals[b];
    int res = -1;
    if (p < total) {
        const int* st = starts + b * NT;
        int lo = 0, hi = NT - 1;
        while (lo < hi) {
            int mid = (lo + hi + 1) >> 1;
            if (st[mid] <= p) lo = mid; else hi = mid - 1;
        }
        res = lo;
    }
    tok[gid] = res;
}

// ---------------- decoder conv3: [B,2048,128] -> wav [B,2048] ----------------
__global__ __launch_bounds__(256) void conv3_kernel(const float* __restrict__ in,
                                                    const float* __restrict__ w,
                                                    const float* __restrict__ bias,
                                                    float* __restrict__ out)
{
    const int gid = blockIdx.x * 256 + threadIdx.x;   // 65536
    const int b = gid >> 11, t = gid & (TOUT - 1);
    float acc = bias[0];
#pragma unroll
    for (int k = 0; k < 5; ++k) {
        int t2 = t + k - 2;
        if (t2 < 0 || t2 >= TOUT) continue;
        const float* row = in + ((size_t)b * TOUT + t2) * 128;
        for (int c = 0; c < 128; ++c) acc = fmaf(row[c], w[c * 5 + k], acc);
    }
    out[gid] = acc;
}

// ---------------- orchestration ----------------
extern "C" void kernel_launch(void* const* d_in, const int* in_sizes, int n_in,
                              void* d_out, int out_size, void* d_ws, size_t ws_size,
                              hipStream_t stream)
{
    const int*   text    = (const int*)d_in[0];
    const float* emotion = (const float*)d_in[1];
    const float* emb     = (const float*)d_in[2];
    const float* Wqkv    = (const float*)d_in[3];
    const float* bqkv    = (const float*)d_in[4];
    const float* Wo      = (const float*)d_in[5];
    const float* bo      = (const float*)d_in[6];
    const float* W1      = (const float*)d_in[7];
    const float* b1      = (const float*)d_in[8];
    const float* W2      = (const float*)d_in[9];
    const float* b2      = (const float*)d_in[10];
    const float* ln1g    = (const float*)d_in[11];
    const float* ln1b    = (const float*)d_in[12];
    const float* ln2g    = (const float*)d_in[13];
    const float* ln2b    = (const float*)d_in[14];
    const float* We1     = (const float*)d_in[15];
    const float* be1     = (const float*)d_in[16];
    const float* We2     = (const float*)d_in[17];
    const float* be2     = (const float*)d_in[18];
    const float* dp_w1   = (const float*)d_in[19];
    const float* dp_b1   = (const float*)d_in[20];
    const float* dp_g1   = (const float*)d_in[21];
    const float* dp_bt1  = (const float*)d_in[22];
    const float* dp_m1   = (const float*)d_in[23];
    const float* dp_v1   = (const float*)d_in[24];
    const float* dp_w2   = (const float*)d_in[25];
    const float* dp_b2   = (const float*)d_in[26];
    const float* dp_g2   = (const float*)d_in[27];
    const float* dp_bt2  = (const float*)d_in[28];
    const float* dp_m2   = (const float*)d_in[29];
    const float* dp_v2   = (const float*)d_in[30];
    const float* dp_wo   = (const float*)d_in[31];
    const float* dp_bo   = (const float*)d_in[32];
    const float* dec_w1  = (const float*)d_in[33];
    const float* dec_b1  = (const float*)d_in[34];
    const float* dec_w2  = (const float*)d_in[35];
    const float* dec_b2  = (const float*)d_in[36];
    const float* dec_w3  = (const float*)d_in[37];
    const float* dec_b3  = (const float*)d_in[38];

    float* ws   = (float*)d_ws;
    float* x    = ws + OFF_X;
    float* ffh  = ws + OFF_FFH;
    float* qkvb = ws + OFF_QKV;
    float* attb = ws + OFF_ATTN;
    float* prjb = ws + OFF_PROJ;
    float* ebuf = ws + OFF_E;
    int*   ip     = (int*)(ws + OFF_INT);
    int*   durb   = ip;
    int*   startb = ip + 16384;
    int*   totb   = ip + 32768;
    int*   tokb   = ip + 32832;

    const int M = NB * NT;   // 16384

    embed_kernel<<<M, 256, 0, stream>>>(text, emb, x);

    for (int l = 0; l < NLAYER; ++l) {
        gemm64_kernel<false><<<dim3(12, M / 64), 64, 0, stream>>>(
            x, Wqkv + (size_t)l * ND * 3 * ND, bqkv + l * 3 * ND, qkvb, M, 3 * ND, ND);
        attn2_kernel<<<dim3(NT / 64, NH, NB), 256, 0, stream>>>(qkvb, attb);
        gemm64_kernel<false><<<dim3(4, M / 64), 64, 0, stream>>>(
            attb, Wo + (size_t)l * ND * ND, bo + l * ND, prjb, M, ND, ND);
        add_ln_kernel<<<M, 256, 0, stream>>>(x, prjb, ln1g + l * ND, ln1b + l * ND);
        gemm64_kernel<true><<<dim3(16, M / 64), 64, 0, stream>>>(
            x, W1 + (size_t)l * ND * 4 * ND, b1 + l * 4 * ND, ffh, M, 4 * ND, ND);
        gemm64_kernel<false><<<dim3(4, M / 64), 64, 0, stream>>>(
            ffh, W2 + (size_t)l * 4 * ND * ND, b2 + l * ND, prjb, M, ND, 4 * ND);
        add_ln_kernel<<<M, 256, 0, stream>>>(x, prjb, ln2g + l * ND, ln2b + l * ND);
    }

    emotion_kernel<<<NB, 256, 0, stream>>>(emotion, We1, be1, We2, be2, ebuf);
    addfuse_kernel<<<M, 256, 0, stream>>>(x, ebuf);

    conv_kernel<256, 256, 3, 32, true, true, false><<<dim3(NT / 32, NB), 256, 0, stream>>>(
        x, dp_w1, dp_b1, dp_g1, dp_bt1, dp_m1, dp_v1, nullptr, attb, NT, NT);
    conv_kernel<256, 256, 3, 32, true, true, false><<<dim3(NT / 32, NB), 256, 0, stream>>>(
        attb, dp_w2, dp_b2, dp_g2, dp_bt2, dp_m2, dp_v2, nullptr, prjb, NT, NT);
    dur_kernel<<<M, 256, 0, stream>>>(prjb, dp_wo, dp_bo, durb);
    scan_kernel<<<1, 64, 0, stream>>>(durb, startb, totb);
    tok_kernel<<<NB * TOUT / 256, 256, 0, stream>>>(startb, totb, tokb);

    conv_kernel<256, 256, 5, 32, true, false, true><<<dim3(TOUT / 32, NB), 256, 0, stream>>>(
        x, dec_w1, dec_b1, nullptr, nullptr, nullptr, nullptr, tokb, ffh, TOUT, NT);
    conv_kernel<256, 128, 5, 32, true, false, false><<<dim3(TOUT / 32, NB), 128, 0, stream>>>(
        ffh, dec_w2, dec_b2, nullptr, nullptr, nullptr, nullptr, nullptr, qkvb, TOUT, TOUT);
    conv3_kernel<<<NB * TOUT / 256, 256, 0, stream>>>(qkvb, dec_w3, dec_b3, (float*)d_out);
}